// Round 2
// baseline (334.800 us; speedup 1.0000x reference)
//
#include <hip/hip_runtime.h>
#include <cmath>

// ---------------------------------------------------------------------------
// JPEG compress (YCbCr + 2x2 chroma pool + 8x8 DCT + quantize/round).
//
// Numerics contract (VERIFIED r4/r6, absmax 0.0): f32 end-to-end, every
// accumulation step is mul-then-add with TWO roundings (no FMA). All
// value-path mul/add/sub are inline-asm v_mul_f32 / v_add_f32 / v_sub_f32
// (asm boundary blocks FMA formation). fdiv/rint stay as builtins.
//
// Recipe per output (DO NOT CHANGE):
//   t_c   = rn(x_c * 255)
//   y     = chain c=R,G,B: a = rn(a + rn(t_c*k_c));  X = rn(a - 128)
//   cb/cr = same chain + 128; pool ((p00+p01)+p10)+p11 * 0.25; - 128
//   dct_i = 64-step chain j=(x,y) row-major from 0: a = rn(a + rn(T_ij*X_j))
//   outv  = rintf( rn( rn(sc_i * dct_i) / q_i ) )
//
// R8->R9 RESTRUCTURE (kills the LDS broadcast bottleneck): r8 counters showed
// the DCT loop's wave-uniform ds_read_b128 broadcasts occupied the LDS
// data-return pipe ~80% of kernel time (384 reads/wave x 12cyc x 32 waves/CU
// ~= 61us of 78us). New shape: ONE 8x8 BLOCK PER LANE.
//   - 196,608 blocks = 3072 waves exactly. grid 768 x 256, no LDS, no barriers.
//   - lane loads its block's pixels from global (L1/L3-served), computes X[64]
//     into VGPRs; DCT loops i=0..63 (wave-uniform) with T-row/sc/q via s_load
//     (SGPR); v_mul_f32 v,s,v keeps the mandated two-rounding chain bitwise.
//   - waves homogeneous (Y / Cb / Cr) via readfirstlane'd wave id -> scalar
//     branch; per-image wave packing keeps chroma re-reads cache-local.
//   - stores: each lane writes its own 256B block as 16 float4 stores.
// ---------------------------------------------------------------------------

namespace jc {

constexpr double c1 = 0.98078528040323044912618223613424;  // cos(1*pi/16)
constexpr double c2 = 0.92387953251128675612818318939679;  // cos(2*pi/16)
constexpr double c3 = 0.83146961230254523707878837761791;  // cos(3*pi/16)
constexpr double c4 = 0.70710678118654752440084436210485;  // cos(4*pi/16)
constexpr double c5 = 0.55557023301960222474283081394853;  // cos(5*pi/16)
constexpr double c6 = 0.38268343236508977172845998403040;  // cos(6*pi/16)
constexpr double c7 = 0.19509032201612826784828486847702;  // cos(7*pi/16)
constexpr double alpha0 = 0.70710678118654746171979706919384;  // 1.0/np.sqrt(2)

struct Tab {
  float tr[4096];  // ROW-major: tr[i*64+j] = f32(CX[x][u]*CX[y][v]), i=(u,v), j=(x,y)
  float sc[64];    // f32(f64(alpha_u*alpha_v)*0.25)
  float yq[64];
  float cq[64];
  constexpr Tab() : tr(), sc(), yq(), cq() {
    const double CX[8][8] = {  // CX[x][u] = cos((2x+1)u*pi/16)
      {1.0,  c1,  c2,  c3,  c4,  c5,  c6,  c7},
      {1.0,  c3,  c6, -c7, -c4, -c1, -c2, -c5},
      {1.0,  c5, -c6, -c1, -c4,  c7,  c2,  c3},
      {1.0,  c7, -c2, -c5,  c4,  c3, -c6, -c1},
      {1.0, -c7, -c2,  c5,  c4, -c3, -c6,  c1},
      {1.0, -c5, -c6,  c1, -c4, -c7,  c2, -c3},
      {1.0, -c3,  c6,  c7, -c4,  c1, -c2,  c5},
      {1.0, -c1,  c2, -c3,  c4, -c5,  c6, -c7}};
    for (int i = 0; i < 64; ++i) {
      const int u = i >> 3, v = i & 7;
      for (int j = 0; j < 64; ++j) {
        const int x = j >> 3, y = j & 7;
        tr[i * 64 + j] = (float)(CX[x][u] * CX[y][v]);  // same values as r8's tt
      }
      const double au = (u == 0) ? alpha0 : 1.0;
      const double av = (v == 0) ? alpha0 : 1.0;
      sc[i] = (float)((au * av) * 0.25);
    }
    const int YT[64] = {
      16, 11, 10, 16, 24, 40, 51, 61,
      12, 12, 14, 19, 26, 58, 60, 55,
      14, 13, 16, 24, 40, 57, 69, 56,
      14, 17, 22, 29, 51, 87, 80, 62,
      18, 22, 37, 56, 68, 109, 103, 77,
      24, 35, 55, 64, 81, 104, 113, 92,
      49, 64, 78, 87, 103, 121, 120, 101,
      72, 92, 95, 98, 112, 100, 103, 99};
    const int CT[64] = {
      17, 18, 24, 47, 99, 99, 99, 99,
      18, 21, 26, 66, 99, 99, 99, 99,
      24, 26, 56, 99, 99, 99, 99, 99,
      47, 66, 99, 99, 99, 99, 99, 99,
      99, 99, 99, 99, 99, 99, 99, 99,
      99, 99, 99, 99, 99, 99, 99, 99,
      99, 99, 99, 99, 99, 99, 99, 99,
      99, 99, 99, 99, 99, 99, 99, 99};
    for (int i = 0; i < 64; ++i) {
      yq[i] = (float)YT[i];
      cq[i] = (float)CT[i];
    }
  }
};

__device__ constexpr Tab TT;

}  // namespace jc

// ---- contraction-proof f32 ops (asm boundary blocks FMA formation) ----
__device__ __forceinline__ float vmul(float a, float b) {
  float r; asm("v_mul_f32 %0, %1, %2" : "=v"(r) : "v"(a), "v"(b)); return r;
}
// SGPR x VGPR multiply: identical arithmetic, keeps wave-uniform T in SGPRs
// (no per-use v_mov). v_mul_f32 dst, s, v is legal (1 SGPR operand).
__device__ __forceinline__ float vmulS(float s, float v) {
  float r; asm("v_mul_f32 %0, %1, %2" : "=v"(r) : "s"(s), "v"(v)); return r;
}
__device__ __forceinline__ float vadd(float a, float b) {
  float r; asm("v_add_f32 %0, %1, %2" : "=v"(r) : "v"(a), "v"(b)); return r;
}
__device__ __forceinline__ float vsubf(float a, float b) {  // a - b
  float r; asm("v_sub_f32 %0, %1, %2" : "=v"(r) : "v"(a), "v"(b)); return r;
}

// chroma chain from pre-scaled t values (tR=rn(R*255) etc.), + 128 shift
__device__ __forceinline__ float chro_t(float tR, float tG, float tB,
                                        float kR, float kG, float kB) {
  float a = vmul(tR, kR);
  a = vadd(a, vmul(tG, kG));
  a = vadd(a, vmul(tB, kB));
  return vadd(a, 128.0f);
}

// load 8 consecutive pixels, pre-scale by 255 (t_c = rn(x_c*255))
__device__ __forceinline__ void ld8(const float* __restrict__ p, float* d) {
  const float4 a = *(const float4*)(p);
  const float4 b = *(const float4*)(p + 4);
  d[0] = vmul(a.x, 255.0f); d[1] = vmul(a.y, 255.0f);
  d[2] = vmul(a.z, 255.0f); d[3] = vmul(a.w, 255.0f);
  d[4] = vmul(b.x, 255.0f); d[5] = vmul(b.y, 255.0f);
  d[6] = vmul(b.z, 255.0f); d[7] = vmul(b.w, 255.0f);
}

// grid: 768 wg x 256 thr = 3072 waves; wave = 64 blocks of one kind.
// per image (96 waves): wv 0..63 Y (block row wv, col=lane),
//                       wv 64..79 Cb (blocks m*64+lane), wv 80..95 Cr.
__global__ __launch_bounds__(256, 4) void jpeg_kernel(const float* __restrict__ img,
                                                      float* __restrict__ out) {
  const int t = threadIdx.x;
  const int lane = t & 63;
  // readfirstlane: makes wave id PROVABLY uniform -> scalar branch, s_load
  // for all table accesses (T rows, sc, q tables).
  const int w = __builtin_amdgcn_readfirstlane(t >> 6);
  const int gw = blockIdx.x * 4 + w;
  const int im = gw / 96;   // image 0..31 (uniform -> scalar div)
  const int wv = gw - im * 96;

  const float* base = img + (size_t)im * 786432;  // 3*512*512
  float X[64];
  unsigned obase;  // float index of this lane's output block
  bool isY;

  if (wv < 64) {
    // ---------------- Y wave: lane owns Y block (row wv, col lane) ----------
    isY = true;
    const float* rp = base + (wv * 8) * 512 + lane * 8;
#pragma unroll
    for (int rr = 0; rr < 8; ++rr) {
      float tR[8], tG[8], tB[8];
      ld8(rp + rr * 512, tR);
      ld8(rp + 262144 + rr * 512, tG);
      ld8(rp + 524288 + rr * 512, tB);
#pragma unroll
      for (int y = 0; y < 8; ++y) {
        float a = vmul(tR[y], 0.299f);
        a = vadd(a, vmul(tG[y], 0.587f));
        a = vadd(a, vmul(tB[y], 0.114f));
        X[rr * 8 + y] = vsubf(a, 128.0f);
      }
    }
    obase = ((unsigned)(im * 4096 + wv * 64 + lane)) << 6;
  } else {
    // ------------- chroma wave: lane owns one Cb or Cr block ---------------
    isY = false;
    const int cwv = wv - 64;
    const bool isCb = (cwv < 16);
    const int m = cwv & 15;
    const int cy = 2 * m + (lane >> 5);  // chroma block row 0..31
    const int cx = lane & 31;            // chroma block col 0..31
    const float kR = isCb ? -0.168736f : 0.5f;
    const float kG = isCb ? -0.331264f : -0.418688f;
    const float kB = isCb ? 0.5f : -0.081312f;
    const float* rp = base + (cy * 16) * 512 + cx * 16;
#pragma unroll
    for (int q = 0; q < 8; ++q) {  // pooled row q <- pixel rows 2q, 2q+1
#pragma unroll
      for (int h = 0; h < 2; ++h) {  // pooled cols 4h..4h+3 <- pixel cols 8h..8h+7
        const float* p0 = rp + (2 * q) * 512 + 8 * h;
        float tR0[8], tR1[8], tG0[8], tG1[8], tB0[8], tB1[8];
        ld8(p0, tR0);           ld8(p0 + 512, tR1);
        ld8(p0 + 262144, tG0);  ld8(p0 + 262144 + 512, tG1);
        ld8(p0 + 524288, tB0);  ld8(p0 + 524288 + 512, tB1);
#pragma unroll
        for (int c2 = 0; c2 < 4; ++c2) {
          const int e = 2 * c2, o = e + 1;
          const float p00 = chro_t(tR0[e], tG0[e], tB0[e], kR, kG, kB);
          const float p01 = chro_t(tR0[o], tG0[o], tB0[o], kR, kG, kB);
          const float p10 = chro_t(tR1[e], tG1[e], tB1[e], kR, kG, kB);
          const float p11 = chro_t(tR1[o], tG1[o], tB1[o], kR, kG, kB);
          const float s = vadd(vadd(vadd(p00, p01), p10), p11);
          X[q * 8 + h * 4 + c2] = vsubf(vmul(s, 0.25f), 128.0f);
        }
      }
    }
    obase = 8388608u + (isCb ? 0u : 2097152u) +
            (((unsigned)(im * 1024 + m * 64 + lane)) << 6);
  }

  // ---------------- DCT + quantize: i wave-uniform, T row in SGPRs ---------
  const float* __restrict__ qt = isY ? jc::TT.yq : jc::TT.cq;  // uniform select
  float* op = out + obase;
#pragma unroll 1
  for (int i0 = 0; i0 < 64; i0 += 4) {
    float ov[4];
#pragma unroll
    for (int ii = 0; ii < 4; ++ii) {
      const int i = i0 + ii;
      const float* __restrict__ trow = jc::TT.tr + i * 64;  // uniform -> s_load
      float acc = 0.0f;
#pragma unroll
      for (int j = 0; j < 64; ++j)
        acc = vadd(acc, vmulS(trow[j], X[j]));  // rn(acc + rn(T*X)), row-major j
      ov[ii] = rintf(__fdiv_rn(vmulS(jc::TT.sc[i], acc), qt[i]));
    }
    float4 v4; v4.x = ov[0]; v4.y = ov[1]; v4.z = ov[2]; v4.w = ov[3];
    *(float4*)(op + i0) = v4;  // lane-local 16B, block fully written over loop
  }
}

extern "C" void kernel_launch(void* const* d_in, const int* in_sizes, int n_in,
                              void* d_out, int out_size, void* d_ws, size_t ws_size,
                              hipStream_t stream) {
  (void)in_sizes; (void)n_in; (void)d_ws; (void)ws_size; (void)out_size;
  const float* img = (const float*)d_in[0];
  float* out = (float*)d_out;
  jpeg_kernel<<<dim3(768), dim3(256), 0, stream>>>(img, out);
}